// Round 16
// baseline (490.407 us; speedup 1.0000x reference)
//
#include <hip/hip_runtime.h>
#include <hip/hip_bf16.h>

#define HID 64
#define MAXNB 2048     // max buckets (N <= 131072)
#define NBLK 512       // radix partition blocks (2 blocks/CU on 256 CUs)
#define FILL_T 1024    // threads for fill
#define HREP 4         // replicated LDS histograms in fill
#define SEG_CAP 2560   // fixed bucket segment capacity (mean 2048, +11 sigma)

__device__ __forceinline__ float bf2f(unsigned short u) {
    return __uint_as_float(((unsigned)u) << 16);
}
__device__ __forceinline__ unsigned short f2bf(float f) {
    __hip_bfloat16 b = __float2bfloat16(f);  // RNE
    return *(unsigned short*)&b;
}
__device__ __forceinline__ unsigned packbf(float lo, float hi) {
    return (unsigned)f2bf(lo) | ((unsigned)f2bf(hi) << 16);
}
__device__ __forceinline__ int ldnt(const int* p) {
    return __builtin_nontemporal_load(p);  // col is single-use: don't pollute L2
}

// ========== single-pass radix partition into fixed-capacity bucket segments ==========
__global__ __launch_bounds__(FILL_T) void radix_fill2_kernel(
    const int* __restrict__ ei, int* __restrict__ gcur,
    unsigned* __restrict__ ebuf, int E, int NB, int C) {
    __shared__ int lh[HREP * (MAXNB + 1)];
    __shared__ int lcur[MAXNB];
    int blk = blockIdx.x, tid = threadIdx.x;
    for (int i = tid; i < HREP * (MAXNB + 1); i += FILL_T) lh[i] = 0;
    __syncthreads();
    int* lhr = lh + ((tid >> 6) & (HREP - 1)) * (MAXNB + 1);
    int lo = blk * C, hi = min(lo + C, E);
    int cnt = hi - lo;
    int n4 = ((E & 3) == 0) ? (cnt >> 2) : 0;  // host guarantees C % 4 == 0
    const int4* d4 = (const int4*)(ei + (long long)E + lo);
    for (int k = tid; k < n4; k += FILL_T) {
        int4 d = d4[k];
        atomicAdd(&lhr[d.x >> 6], 1);
        atomicAdd(&lhr[d.y >> 6], 1);
        atomicAdd(&lhr[d.z >> 6], 1);
        atomicAdd(&lhr[d.w >> 6], 1);
    }
    for (int e = lo + (n4 << 2) + tid; e < hi; e += FILL_T)
        atomicAdd(&lhr[ei[(long long)E + e] >> 6], 1);
    __syncthreads();
    for (int i = tid; i < NB; i += FILL_T) {
        int v = 0;
#pragma unroll
        for (int r = 0; r < HREP; r++) v += lh[r * (MAXNB + 1) + i];
        int start = v ? atomicAdd(&gcur[i], v) : 0;
        lcur[i] = i * SEG_CAP + start;
    }
    __syncthreads();
    const int4* s4 = (const int4*)(ei + lo);
    for (int k = tid; k < n4; k += FILL_T) {
        int4 s = s4[k];
        int4 d = d4[k];
        int p0 = atomicAdd(&lcur[d.x >> 6], 1);
        int p1 = atomicAdd(&lcur[d.y >> 6], 1);
        int p2 = atomicAdd(&lcur[d.z >> 6], 1);
        int p3 = atomicAdd(&lcur[d.w >> 6], 1);
        ebuf[p0] = ((unsigned)s.x << 6) | (unsigned)(d.x & 63);
        ebuf[p1] = ((unsigned)s.y << 6) | (unsigned)(d.y & 63);
        ebuf[p2] = ((unsigned)s.z << 6) | (unsigned)(d.z & 63);
        ebuf[p3] = ((unsigned)s.w << 6) | (unsigned)(d.w & 63);
    }
    for (int e = lo + (n4 << 2) + tid; e < hi; e += FILL_T) {
        int s = ei[e];
        int d = ei[(long long)E + e];
        int pos = atomicAdd(&lcur[d >> 6], 1);
        ebuf[pos] = ((unsigned)s << 6) | (unsigned)(d & 63);
    }
}

// ====== per-bucket counting sort + dinv + xs; block 0 also zeroes sums ======
__global__ __launch_bounds__(256) void node_csr_xs_kernel(
    const int* __restrict__ gcur, const unsigned* __restrict__ ebuf,
    const float* __restrict__ x,
    int* __restrict__ row_ptr, int* __restrict__ rend,
    int* __restrict__ col, float* __restrict__ dinv,
    unsigned short* __restrict__ xs, float* __restrict__ sums, int N, int NB) {
    __shared__ unsigned sE[SEG_CAP];
    __shared__ int lcnt[64];
    __shared__ int lcur[64];
    __shared__ float sDv[64];
    int bkt = blockIdx.x, tid = threadIdx.x;
    if (bkt == 0) {  // zero pooling accumulators (stream-ordered before pool)
        for (int i = tid; i < 128 * HID; i += 256) sums[i] = 0.f;
    }
    int beg = bkt * SEG_CAP;
    int cnt = min(gcur[bkt], SEG_CAP);
    if (tid < 64) lcnt[tid] = 0;
    for (int i = tid; i < cnt; i += 256) sE[i] = ebuf[beg + i];
    __syncthreads();
    for (int i = tid; i < cnt; i += 256) atomicAdd(&lcnt[sE[i] & 63u], 1);
    __syncthreads();
    if (tid < 64) {
        int v = lcnt[tid];
        int p = v;
#pragma unroll
        for (int off = 1; off < 64; off <<= 1) {
            int t = __shfl_up(p, off);
            if (tid >= off) p += t;
        }
        int base = beg + p - v;  // exclusive scan within bucket
        lcur[tid] = base;
        int node = (bkt << 6) + tid;
        float dv = rsqrtf((float)(v + 1));  // +1 self loop
        sDv[tid] = dv;
        if (node < N) {
            row_ptr[node] = base;
            rend[node] = base + v;
            dinv[node] = dv;
        }
    }
    __syncthreads();
    for (int i = tid; i < cnt; i += 256) {
        unsigned ev = sE[i];
        int pos = atomicAdd(&lcur[ev & 63u], 1);
        col[pos] = (int)(ev >> 6);
    }
    // xs epilogue: thread t covers node r = t>>2, feature quad q = t&3
    {
        int r = tid >> 2, q = tid & 3;
        int node = (bkt << 6) + r;
        if (node < N) {
            float dv = sDv[r];
            float4 xv = *(const float4*)(x + (long long)node * 16 + q * 4);
            uint2 w;
            w.x = packbf(dv * xv.x, dv * xv.y);
            w.y = packbf(dv * xv.z, dv * xv.w);
            *(uint2*)(xs + (long long)node * 16 + q * 4) = w;
        }
    }
}

// ================= 16-dim gather: agg[dst] = sum_{src in N(dst)+self} xs[src] ====
__device__ __forceinline__ void add4(float* acc, uint2 r) {
    acc[0] += __uint_as_float(r.x << 16);
    acc[1] += __uint_as_float(r.x & 0xffff0000u);
    acc[2] += __uint_as_float(r.y << 16);
    acc[3] += __uint_as_float(r.y & 0xffff0000u);
}

__global__ __launch_bounds__(256) void gather16_kernel(
    const int* __restrict__ row_ptr, const int* __restrict__ rend,
    const int* __restrict__ col,
    const unsigned short* __restrict__ xs, float* __restrict__ agg, int N) {
    int wv = __builtin_amdgcn_readfirstlane(threadIdx.x >> 6);
    int node = blockIdx.x * 4 + wv;
    int lane = threadIdx.x & 63;
    if (node >= N) return;
    int grp = lane >> 2;  // 16 edge groups
    int c = lane & 3;     // feature-pair chunk
    int beg = row_ptr[node], end = rend[node];

    float acc[4] = {0.f, 0.f, 0.f, 0.f};
    if (grp == 0) {  // self loop: lanes 0..3 cover all 16 features
        uint2 rs = *(const uint2*)(xs + ((long long)node << 4) + (c << 2));
        add4(acc, rs);
    }
    for (int base = beg; base < end; base += 32) {
        int e0 = base + grp;
        int e1 = e0 + 16;
        bool k0 = e0 < end, k1 = e1 < end;
        int c0 = k0 ? ldnt(col + e0) : 0;
        int c1 = k1 ? ldnt(col + e1) : 0;
        uint2 r0 = *(const uint2*)(xs + (((long long)c0) << 4) + (c << 2));
        uint2 r1 = *(const uint2*)(xs + (((long long)c1) << 4) + (c << 2));
        if (k0) add4(acc, r0);
        if (k1) add4(acc, r1);
    }
#pragma unroll
    for (int m = 4; m <= 32; m <<= 1) {
#pragma unroll
        for (int k = 0; k < 4; k++) acc[k] += __shfl_xor(acc[k], m);
    }
    if (lane < 4) {  // grp == 0, lane == c
        float4 w = make_float4(acc[0], acc[1], acc[2], acc[3]);
        *(float4*)(agg + ((long long)node << 4) + (lane << 2)) = w;
    }
}

// ====== fused layer-1+2 gemm: h1 = relu(dinv*(agg@W1)+b1) in LDS (f32),
//        g2 = bf16(dinv * (h1 @ W2)). ======
__global__ __launch_bounds__(256) void gemm_agg2_kernel(
    const float* __restrict__ agg,
    const float* __restrict__ W1, const float* __restrict__ b1,
    const float* __restrict__ W2,
    const float* __restrict__ dinv, unsigned short* __restrict__ g2, int N) {
    __shared__ float sW1[16 * HID];
    __shared__ float sW2[HID * HID];
    __shared__ float sIn[16 * 16];
    __shared__ float sH[16 * HID];
    __shared__ float sB1[HID];
    __shared__ float sDv[16];
    int tid = threadIdx.x;
    for (int i = tid; i < 16 * HID; i += 256) sW1[i] = W1[i];
    for (int i = tid; i < HID * HID; i += 256) sW2[i] = W2[i];
    if (tid < HID) sB1[tid] = b1[tid];
    int base = blockIdx.x * 16;
    {
        int r = tid >> 4, c = tid & 15;
        int node = base + r;
        sIn[tid] = (node < N) ? agg[(long long)node * 16 + c] : 0.f;
    }
    if (tid < 16) {
        int node = base + tid;
        sDv[tid] = (node < N) ? dinv[node] : 0.f;
    }
    __syncthreads();
    int j = tid & 63;
    int si = tid >> 6;
#pragma unroll
    for (int u = 0; u < 4; u++) {
        int r = si * 4 + u;
        float acc = 0.f;
#pragma unroll
        for (int k = 0; k < 16; k++) acc += sIn[r * 16 + k] * sW1[k * HID + j];
        float v = sDv[r] * acc + sB1[j];
        sH[r * HID + j] = v > 0.f ? v : 0.f;
    }
    __syncthreads();
#pragma unroll
    for (int u = 0; u < 4; u++) {
        int r = si * 4 + u;
        int node = base + r;
        if (node >= N) continue;
        float acc = 0.f;
#pragma unroll 16
        for (int k = 0; k < HID; k++) acc += sH[r * HID + k] * sW2[k * HID + j];
        g2[(long long)node * HID + j] = f2bf(sDv[r] * acc);
    }
}

// ================= g = bf16(dinv * (in @ W)) =================
template <typename Tin, int K>
__global__ void gemm_g_kernel(const Tin* __restrict__ in,
                              const float* __restrict__ W,
                              const float* __restrict__ dinv,
                              unsigned short* __restrict__ g, int N) {
    __shared__ float sW[K * HID];
    __shared__ float sIn[16 * K];
    int tid = threadIdx.x;
    for (int idx = tid; idx < K * HID; idx += 256) sW[idx] = W[idx];
    int base = blockIdx.x * 16;
    for (int idx = tid; idx < 16 * K; idx += 256) {
        int r = idx / K, c = idx % K;
        int node = base + r;
        float v = 0.f;
        if (node < N) {
            Tin t = in[(long long)node * K + c];
            if constexpr (sizeof(Tin) == 2) v = bf2f((unsigned short)t);
            else v = (float)t;
        }
        sIn[idx] = v;
    }
    __syncthreads();
    int j = tid & 63;
    int si = tid >> 6;
#pragma unroll
    for (int u = 0; u < 4; u++) {
        int r = si * 4 + u;
        int node = base + r;
        if (node >= N) continue;
        float acc = 0.f;
#pragma unroll
        for (int k = 0; k < K; k++) acc += sIn[r * K + k] * sW[k * HID + j];
        g[(long long)node * HID + j] = f2bf(dinv[node] * acc);
    }
}

// ================= gather + combine: 8 rows per VMEM =================
__device__ __forceinline__ void add8(float* acc, uint4 r) {
    acc[0] += __uint_as_float(r.x << 16);
    acc[1] += __uint_as_float(r.x & 0xffff0000u);
    acc[2] += __uint_as_float(r.y << 16);
    acc[3] += __uint_as_float(r.y & 0xffff0000u);
    acc[4] += __uint_as_float(r.z << 16);
    acc[5] += __uint_as_float(r.z & 0xffff0000u);
    acc[6] += __uint_as_float(r.w << 16);
    acc[7] += __uint_as_float(r.w & 0xffff0000u);
}

__global__ __launch_bounds__(256) void gather_kernel(
    const int* __restrict__ row_ptr, const int* __restrict__ rend,
    const int* __restrict__ col,
    const unsigned short* __restrict__ g, const float* __restrict__ dinv,
    const float* __restrict__ bias, unsigned short* __restrict__ h, int N) {
    int wv = __builtin_amdgcn_readfirstlane(threadIdx.x >> 6);  // force wave-uniform
    int node = blockIdx.x * 4 + wv;
    int lane = threadIdx.x & 63;
    if (node >= N) return;
    int grp = lane >> 3;
    int c = lane & 7;
    int beg = row_ptr[node], end = rend[node];

    float acc[8] = {0.f, 0.f, 0.f, 0.f, 0.f, 0.f, 0.f, 0.f};
    if (grp == 0) {
        uint4 rs = *(const uint4*)(g + ((long long)node << 6) + (c << 3));
        add8(acc, rs);
    }
    for (int base = beg; base < end; base += 32) {
        int e0 = base + grp;
        int e1 = e0 + 8, e2 = e0 + 16, e3 = e0 + 24;
        bool k0 = e0 < end, k1 = e1 < end, k2 = e2 < end, k3 = e3 < end;
        int c0 = k0 ? ldnt(col + e0) : 0;
        int c1 = k1 ? ldnt(col + e1) : 0;
        int c2 = k2 ? ldnt(col + e2) : 0;
        int c3 = k3 ? ldnt(col + e3) : 0;
        uint4 r0 = *(const uint4*)(g + (((long long)c0) << 6) + (c << 3));
        uint4 r1 = *(const uint4*)(g + (((long long)c1) << 6) + (c << 3));
        uint4 r2 = *(const uint4*)(g + (((long long)c2) << 6) + (c << 3));
        uint4 r3 = *(const uint4*)(g + (((long long)c3) << 6) + (c << 3));
        if (k0) add8(acc, r0);
        if (k1) add8(acc, r1);
        if (k2) add8(acc, r2);
        if (k3) add8(acc, r3);
    }
#pragma unroll
    for (int m = 8; m <= 32; m <<= 1) {
#pragma unroll
        for (int k = 0; k < 8; k++) acc[k] += __shfl_xor(acc[k], m);
    }
    if (lane < 8) {
        float dv = dinv[node];
        float4 ba = *(const float4*)(bias + (lane << 3));
        float4 bb = *(const float4*)(bias + (lane << 3) + 4);
        float v0 = dv * acc[0] + ba.x;
        float v1 = dv * acc[1] + ba.y;
        float v2 = dv * acc[2] + ba.z;
        float v3 = dv * acc[3] + ba.w;
        float v4 = dv * acc[4] + bb.x;
        float v5 = dv * acc[5] + bb.y;
        float v6 = dv * acc[6] + bb.z;
        float v7 = dv * acc[7] + bb.w;
        v0 = v0 > 0.f ? v0 : 0.f;
        v1 = v1 > 0.f ? v1 : 0.f;
        v2 = v2 > 0.f ? v2 : 0.f;
        v3 = v3 > 0.f ? v3 : 0.f;
        v4 = v4 > 0.f ? v4 : 0.f;
        v5 = v5 > 0.f ? v5 : 0.f;
        v6 = v6 > 0.f ? v6 : 0.f;
        v7 = v7 > 0.f ? v7 : 0.f;
        uint4 w;
        w.x = (unsigned)f2bf(v0) | ((unsigned)f2bf(v1) << 16);
        w.y = (unsigned)f2bf(v2) | ((unsigned)f2bf(v3) << 16);
        w.z = (unsigned)f2bf(v4) | ((unsigned)f2bf(v5) << 16);
        w.w = (unsigned)f2bf(v6) | ((unsigned)f2bf(v7) << 16);
        *(uint4*)(h + ((long long)node << 6) + (lane << 3)) = w;
    }
}

// ========== pooling: segmented reduction over sorted batch (sums only) ==========
__global__ void pool_kernel(const unsigned short* __restrict__ h, const int* __restrict__ batch,
                            float* __restrict__ sums, int N) {
    int wave = blockIdx.x * 4 + (threadIdx.x >> 6);
    int lane = threadIdx.x & 63;
    int lo = wave * 16;
    if (lo >= N) return;
    int hi = min(lo + 16, N);
    int curb = batch[lo];
    float sum = 0.f;
    for (int i = lo; i < hi; i++) {
        int b = batch[i];
        if (b != curb) {
            atomicAdd(&sums[curb * HID + lane], sum);
            curb = b; sum = 0.f;
        }
        sum += bf2f(h[(long long)i * HID + lane]);
    }
    atomicAdd(&sums[curb * HID + lane], sum);
}

// ================= final MLP head (cnt via binary search on sorted batch) =========
__global__ void final_kernel(const float* __restrict__ sums, const int* __restrict__ batch,
                             const float* __restrict__ Wf1, const float* __restrict__ bf1,
                             const float* __restrict__ Wf2, const float* __restrict__ bf2,
                             float* __restrict__ out, int N) {
    __shared__ float sW1[HID * 32];
    __shared__ float sW2[32];
    __shared__ int sUB[128];
    int tid = threadIdx.x;
    for (int idx = tid; idx < HID * 32; idx += 128) sW1[idx] = Wf1[idx];
    if (tid < 32) sW2[tid] = Wf2[tid];
    // upper_bound(batch, tid): first index with batch[i] > tid
    {
        int lo = 0, hi = N;
        while (lo < hi) {
            int mid = (lo + hi) >> 1;
            if (batch[mid] <= tid) lo = mid + 1; else hi = mid;
        }
        sUB[tid] = lo;
    }
    __syncthreads();
    int b = tid;
    float c = (float)(sUB[b] - (b ? sUB[b - 1] : 0));
    c = fmaxf(c, 1.0f);
    float pooled[HID];
#pragma unroll
    for (int j = 0; j < HID; j++) pooled[j] = sums[b * HID + j] / c;
    float o = bf2[0];
#pragma unroll 4
    for (int hd = 0; hd < 32; hd++) {
        float z = bf1[hd];
#pragma unroll
        for (int j = 0; j < HID; j++) z += pooled[j] * sW1[j * 32 + hd];
        z = fmaxf(z, 0.f);
        o += z * sW2[hd];
    }
    out[b] = o;
}

extern "C" void kernel_launch(void* const* d_in, const int* in_sizes, int n_in,
                              void* d_out, int out_size, void* d_ws, size_t ws_size,
                              hipStream_t stream) {
    const float* x     = (const float*)d_in[0];
    const int*   ei    = (const int*)d_in[1];
    const int*   batch = (const int*)d_in[3];
    const float* W1  = (const float*)d_in[4];
    const float* b1  = (const float*)d_in[5];
    const float* W2  = (const float*)d_in[6];
    const float* b2  = (const float*)d_in[7];
    const float* W3  = (const float*)d_in[8];
    const float* b3  = (const float*)d_in[9];
    const float* Wf1 = (const float*)d_in[10];
    const float* bf1 = (const float*)d_in[11];
    const float* Wf2 = (const float*)d_in[12];
    const float* bf2 = (const float*)d_in[13];
    float* out = (float*)d_out;

    const int N  = in_sizes[0] / 16;   // 100000
    const int E  = in_sizes[1] / 2;    // 3200000
    const int NB = (N + 63) / 64;      // 1563 buckets

    // workspace layout (~72 MB), fixed-capacity padded ebuf/col segments
    char* ws = (char*)d_ws;
    size_t o = 0;
    float*          dinv    = (float*)(ws + o);          o += ((size_t)N * 4 + 4095) / 4096 * 4096;
    int*            row_ptr = (int*)(ws + o);            o += ((size_t)N * 4 + 4095) / 4096 * 4096;
    int*            rend    = (int*)(ws + o);            o += ((size_t)N * 4 + 4095) / 4096 * 4096;
    int*            gcur    = (int*)(ws + o);            o += ((size_t)NB * 4 + 4095) / 4096 * 4096;
    unsigned*       ebuf    = (unsigned*)(ws + o);       o += (size_t)NB * SEG_CAP * 4;
    int*            col     = (int*)(ws + o);            o += (size_t)NB * SEG_CAP * 4;
    unsigned short* A       = (unsigned short*)(ws + o); o += (size_t)N * HID * 2;
    unsigned short* B       = (unsigned short*)(ws + o); o += (size_t)N * HID * 2;
    unsigned short* XS      = (unsigned short*)(ws + o); o += ((size_t)N * 16 * 2 + 4095) / 4096 * 4096;
    float*          AGG     = (float*)(ws + o);          o += ((size_t)N * 16 * 4 + 4095) / 4096 * 4096;
    float*          sums    = (float*)(ws + o);          o += 128 * HID * 4;
    (void)ws_size;

    const int T = 256;
    const int Cchunk = (((E + NBLK - 1) / NBLK) + 3) & ~3;   // mult of 4 for int4 loads
    const int gGm = (N + 15) / 16;
    const int gGa = (N + 3) / 4;
    const int gPool = ((N + 15) / 16 + 3) / 4;

    // ---- CSR build: single-pass padded radix partition + per-bucket sort ----
    hipMemsetAsync(gcur, 0, (size_t)NB * 4, stream);
    radix_fill2_kernel<<<NBLK, FILL_T, 0, stream>>>(ei, gcur, ebuf, E, NB, Cchunk);
    node_csr_xs_kernel<<<NB, T, 0, stream>>>(gcur, ebuf, x, row_ptr, rend, col, dinv, XS, sums, N, NB);

    // ---- layer 1+2 front: agg in 16-dim input space (L2-resident), then
    //      fused (agg@W1 -> relu -> @W2) producing g2 directly ----
    gather16_kernel<<<gGa, T, 0, stream>>>(row_ptr, rend, col, XS, AGG, N);
    gemm_agg2_kernel<<<gGm, T, 0, stream>>>(AGG, W1, b1, W2, dinv, A, N);

    // ---- layer 2 back: gather g2 -> h2 ----
    gather_kernel<<<gGa, T, 0, stream>>>(row_ptr, rend, col, A, dinv, b2, B, N);

    // ---- layer 3: h2 -> g3 (in-place) -> gather -> h3 ----
    gemm_g_kernel<unsigned short, 64><<<gGm, T, 0, stream>>>(B, W3, dinv, B, N);
    gather_kernel<<<gGa, T, 0, stream>>>(row_ptr, rend, col, B, dinv, b3, A, N);

    // ---- pool + head ----
    pool_kernel<<<gPool, T, 0, stream>>>(A, batch, sums, N);
    final_kernel<<<1, 128, 0, stream>>>(sums, batch, Wf1, bf1, Wf2, bf2, out, N);
}

// Round 18
// 468.011 us; speedup vs baseline: 1.0479x; 1.0479x over previous
//
#include <hip/hip_runtime.h>
#include <hip/hip_bf16.h>

#define HID 64
#define MAXNB 2048     // max buckets (N <= 131072)
#define NBLK 512       // radix partition blocks (2 blocks/CU on 256 CUs)
#define FILL_T 1024    // threads for fill
#define HREP 4         // replicated LDS histograms in fill
#define SEG_CAP 2560   // fixed bucket segment capacity (mean 2048, +11 sigma)

__device__ __forceinline__ float bf2f(unsigned short u) {
    return __uint_as_float(((unsigned)u) << 16);
}
__device__ __forceinline__ unsigned short f2bf(float f) {
    __hip_bfloat16 b = __float2bfloat16(f);  // RNE
    return *(unsigned short*)&b;
}
__device__ __forceinline__ unsigned packbf(float lo, float hi) {
    return (unsigned)f2bf(lo) | ((unsigned)f2bf(hi) << 16);
}

// ========== single-pass radix partition into fixed-capacity bucket segments ==========
__global__ __launch_bounds__(FILL_T) void radix_fill2_kernel(
    const int* __restrict__ ei, int* __restrict__ gcur,
    unsigned* __restrict__ ebuf, int E, int NB, int C) {
    __shared__ int lh[HREP * (MAXNB + 1)];
    __shared__ int lcur[MAXNB];
    int blk = blockIdx.x, tid = threadIdx.x;
    for (int i = tid; i < HREP * (MAXNB + 1); i += FILL_T) lh[i] = 0;
    __syncthreads();
    int* lhr = lh + ((tid >> 6) & (HREP - 1)) * (MAXNB + 1);
    int lo = blk * C, hi = min(lo + C, E);
    int cnt = hi - lo;
    int n4 = ((E & 3) == 0) ? (cnt >> 2) : 0;  // host guarantees C % 4 == 0
    const int4* d4 = (const int4*)(ei + (long long)E + lo);
    for (int k = tid; k < n4; k += FILL_T) {
        int4 d = d4[k];
        atomicAdd(&lhr[d.x >> 6], 1);
        atomicAdd(&lhr[d.y >> 6], 1);
        atomicAdd(&lhr[d.z >> 6], 1);
        atomicAdd(&lhr[d.w >> 6], 1);
    }
    for (int e = lo + (n4 << 2) + tid; e < hi; e += FILL_T)
        atomicAdd(&lhr[ei[(long long)E + e] >> 6], 1);
    __syncthreads();
    for (int i = tid; i < NB; i += FILL_T) {
        int v = 0;
#pragma unroll
        for (int r = 0; r < HREP; r++) v += lh[r * (MAXNB + 1) + i];
        int start = v ? atomicAdd(&gcur[i], v) : 0;
        lcur[i] = i * SEG_CAP + start;
    }
    __syncthreads();
    const int4* s4 = (const int4*)(ei + lo);
    for (int k = tid; k < n4; k += FILL_T) {
        int4 s = s4[k];
        int4 d = d4[k];
        int p0 = atomicAdd(&lcur[d.x >> 6], 1);
        int p1 = atomicAdd(&lcur[d.y >> 6], 1);
        int p2 = atomicAdd(&lcur[d.z >> 6], 1);
        int p3 = atomicAdd(&lcur[d.w >> 6], 1);
        ebuf[p0] = ((unsigned)s.x << 6) | (unsigned)(d.x & 63);
        ebuf[p1] = ((unsigned)s.y << 6) | (unsigned)(d.y & 63);
        ebuf[p2] = ((unsigned)s.z << 6) | (unsigned)(d.z & 63);
        ebuf[p3] = ((unsigned)s.w << 6) | (unsigned)(d.w & 63);
    }
    for (int e = lo + (n4 << 2) + tid; e < hi; e += FILL_T) {
        int s = ei[e];
        int d = ei[(long long)E + e];
        int pos = atomicAdd(&lcur[d >> 6], 1);
        ebuf[pos] = ((unsigned)s << 6) | (unsigned)(d & 63);
    }
}

// ====== per-bucket counting sort + dinv + xs; block 0 also zeroes sums ======
__global__ __launch_bounds__(256) void node_csr_xs_kernel(
    const int* __restrict__ gcur, const unsigned* __restrict__ ebuf,
    const float* __restrict__ x,
    int* __restrict__ row_ptr, int* __restrict__ rend,
    int* __restrict__ col, float* __restrict__ dinv,
    unsigned short* __restrict__ xs, float* __restrict__ sums, int N, int NB) {
    __shared__ unsigned sE[SEG_CAP];
    __shared__ int lcnt[64];
    __shared__ int lcur[64];
    __shared__ float sDv[64];
    int bkt = blockIdx.x, tid = threadIdx.x;
    if (bkt == 0) {  // zero pooling accumulators (stream-ordered before pool)
        for (int i = tid; i < 128 * HID; i += 256) sums[i] = 0.f;
    }
    int beg = bkt * SEG_CAP;
    int cnt = min(gcur[bkt], SEG_CAP);
    if (tid < 64) lcnt[tid] = 0;
    for (int i = tid; i < cnt; i += 256) sE[i] = ebuf[beg + i];
    __syncthreads();
    for (int i = tid; i < cnt; i += 256) atomicAdd(&lcnt[sE[i] & 63u], 1);
    __syncthreads();
    if (tid < 64) {
        int v = lcnt[tid];
        int p = v;
#pragma unroll
        for (int off = 1; off < 64; off <<= 1) {
            int t = __shfl_up(p, off);
            if (tid >= off) p += t;
        }
        int base = beg + p - v;  // exclusive scan within bucket
        lcur[tid] = base;
        int node = (bkt << 6) + tid;
        float dv = rsqrtf((float)(v + 1));  // +1 self loop
        sDv[tid] = dv;
        if (node < N) {
            row_ptr[node] = base;
            rend[node] = base + v;
            dinv[node] = dv;
        }
    }
    __syncthreads();
    for (int i = tid; i < cnt; i += 256) {
        unsigned ev = sE[i];
        int pos = atomicAdd(&lcur[ev & 63u], 1);
        col[pos] = (int)(ev >> 6);
    }
    // xs epilogue: thread t covers node r = t>>2, feature quad q = t&3
    {
        int r = tid >> 2, q = tid & 3;
        int node = (bkt << 6) + r;
        if (node < N) {
            float dv = sDv[r];
            float4 xv = *(const float4*)(x + (long long)node * 16 + q * 4);
            uint2 w;
            w.x = packbf(dv * xv.x, dv * xv.y);
            w.y = packbf(dv * xv.z, dv * xv.w);
            *(uint2*)(xs + (long long)node * 16 + q * 4) = w;
        }
    }
}

// ================= 16-dim gather: agg[dst] = sum_{src in N(dst)+self} xs[src] ====
__device__ __forceinline__ void add4(float* acc, uint2 r) {
    acc[0] += __uint_as_float(r.x << 16);
    acc[1] += __uint_as_float(r.x & 0xffff0000u);
    acc[2] += __uint_as_float(r.y << 16);
    acc[3] += __uint_as_float(r.y & 0xffff0000u);
}

__global__ __launch_bounds__(256) void gather16_kernel(
    const int* __restrict__ row_ptr, const int* __restrict__ rend,
    const int* __restrict__ col,
    const unsigned short* __restrict__ xs, float* __restrict__ agg, int N) {
    int wv = __builtin_amdgcn_readfirstlane(threadIdx.x >> 6);
    int node = blockIdx.x * 4 + wv;
    int lane = threadIdx.x & 63;
    if (node >= N) return;
    int grp = lane >> 2;  // 16 edge groups
    int c = lane & 3;     // feature-pair chunk
    int beg = row_ptr[node], end = rend[node];

    float acc[4] = {0.f, 0.f, 0.f, 0.f};
    if (grp == 0) {  // self loop: lanes 0..3 cover all 16 features
        uint2 rs = *(const uint2*)(xs + ((long long)node << 4) + (c << 2));
        add4(acc, rs);
    }
    for (int base = beg; base < end; base += 32) {
        int e0 = base + grp;
        int e1 = e0 + 16;
        bool k0 = e0 < end, k1 = e1 < end;
        int c0 = k0 ? col[e0] : 0;
        int c1 = k1 ? col[e1] : 0;
        uint2 r0 = *(const uint2*)(xs + (((long long)c0) << 4) + (c << 2));
        uint2 r1 = *(const uint2*)(xs + (((long long)c1) << 4) + (c << 2));
        if (k0) add4(acc, r0);
        if (k1) add4(acc, r1);
    }
#pragma unroll
    for (int m = 4; m <= 32; m <<= 1) {
#pragma unroll
        for (int k = 0; k < 4; k++) acc[k] += __shfl_xor(acc[k], m);
    }
    if (lane < 4) {  // grp == 0, lane == c
        float4 w = make_float4(acc[0], acc[1], acc[2], acc[3]);
        *(float4*)(agg + ((long long)node << 4) + (lane << 2)) = w;
    }
}

// ====== fused layer-1+2 gemm: h1 = relu(dinv*(agg@W1)+b1) in LDS (f32),
//        g2 = bf16(dinv * (h1 @ W2)). ======
__global__ __launch_bounds__(256) void gemm_agg2_kernel(
    const float* __restrict__ agg,
    const float* __restrict__ W1, const float* __restrict__ b1,
    const float* __restrict__ W2,
    const float* __restrict__ dinv, unsigned short* __restrict__ g2, int N) {
    __shared__ float sW1[16 * HID];
    __shared__ float sW2[HID * HID];
    __shared__ float sIn[16 * 16];
    __shared__ float sH[16 * HID];
    __shared__ float sB1[HID];
    __shared__ float sDv[16];
    int tid = threadIdx.x;
    for (int i = tid; i < 16 * HID; i += 256) sW1[i] = W1[i];
    for (int i = tid; i < HID * HID; i += 256) sW2[i] = W2[i];
    if (tid < HID) sB1[tid] = b1[tid];
    int base = blockIdx.x * 16;
    {
        int r = tid >> 4, c = tid & 15;
        int node = base + r;
        sIn[tid] = (node < N) ? agg[(long long)node * 16 + c] : 0.f;
    }
    if (tid < 16) {
        int node = base + tid;
        sDv[tid] = (node < N) ? dinv[node] : 0.f;
    }
    __syncthreads();
    int j = tid & 63;
    int si = tid >> 6;
#pragma unroll
    for (int u = 0; u < 4; u++) {
        int r = si * 4 + u;
        float acc = 0.f;
#pragma unroll
        for (int k = 0; k < 16; k++) acc += sIn[r * 16 + k] * sW1[k * HID + j];
        float v = sDv[r] * acc + sB1[j];
        sH[r * HID + j] = v > 0.f ? v : 0.f;
    }
    __syncthreads();
#pragma unroll
    for (int u = 0; u < 4; u++) {
        int r = si * 4 + u;
        int node = base + r;
        if (node >= N) continue;
        float acc = 0.f;
#pragma unroll 16
        for (int k = 0; k < HID; k++) acc += sH[r * HID + k] * sW2[k * HID + j];
        g2[(long long)node * HID + j] = f2bf(sDv[r] * acc);
    }
}

// ================= g = bf16(dinv * (in @ W)) =================
template <typename Tin, int K>
__global__ void gemm_g_kernel(const Tin* __restrict__ in,
                              const float* __restrict__ W,
                              const float* __restrict__ dinv,
                              unsigned short* __restrict__ g, int N) {
    __shared__ float sW[K * HID];
    __shared__ float sIn[16 * K];
    int tid = threadIdx.x;
    for (int idx = tid; idx < K * HID; idx += 256) sW[idx] = W[idx];
    int base = blockIdx.x * 16;
    for (int idx = tid; idx < 16 * K; idx += 256) {
        int r = idx / K, c = idx % K;
        int node = base + r;
        float v = 0.f;
        if (node < N) {
            Tin t = in[(long long)node * K + c];
            if constexpr (sizeof(Tin) == 2) v = bf2f((unsigned short)t);
            else v = (float)t;
        }
        sIn[idx] = v;
    }
    __syncthreads();
    int j = tid & 63;
    int si = tid >> 6;
#pragma unroll
    for (int u = 0; u < 4; u++) {
        int r = si * 4 + u;
        int node = base + r;
        if (node >= N) continue;
        float acc = 0.f;
#pragma unroll
        for (int k = 0; k < K; k++) acc += sIn[r * K + k] * sW[k * HID + j];
        g[(long long)node * HID + j] = f2bf(dinv[node] * acc);
    }
}

// ================= gather + combine: 8 rows per VMEM =================
__device__ __forceinline__ void add8(float* acc, uint4 r) {
    acc[0] += __uint_as_float(r.x << 16);
    acc[1] += __uint_as_float(r.x & 0xffff0000u);
    acc[2] += __uint_as_float(r.y << 16);
    acc[3] += __uint_as_float(r.y & 0xffff0000u);
    acc[4] += __uint_as_float(r.z << 16);
    acc[5] += __uint_as_float(r.z & 0xffff0000u);
    acc[6] += __uint_as_float(r.w << 16);
    acc[7] += __uint_as_float(r.w & 0xffff0000u);
}

__global__ __launch_bounds__(256) void gather_kernel(
    const int* __restrict__ row_ptr, const int* __restrict__ rend,
    const int* __restrict__ col,
    const unsigned short* __restrict__ g, const float* __restrict__ dinv,
    const float* __restrict__ bias, unsigned short* __restrict__ h, int N) {
    int wv = __builtin_amdgcn_readfirstlane(threadIdx.x >> 6);  // force wave-uniform
    int node = blockIdx.x * 4 + wv;
    int lane = threadIdx.x & 63;
    if (node >= N) return;
    int grp = lane >> 3;
    int c = lane & 7;
    int beg = row_ptr[node], end = rend[node];

    float acc[8] = {0.f, 0.f, 0.f, 0.f, 0.f, 0.f, 0.f, 0.f};
    if (grp == 0) {
        uint4 rs = *(const uint4*)(g + ((long long)node << 6) + (c << 3));
        add8(acc, rs);
    }
    for (int base = beg; base < end; base += 32) {
        int e0 = base + grp;
        int e1 = e0 + 8, e2 = e0 + 16, e3 = e0 + 24;
        bool k0 = e0 < end, k1 = e1 < end, k2 = e2 < end, k3 = e3 < end;
        int c0 = k0 ? col[e0] : 0;
        int c1 = k1 ? col[e1] : 0;
        int c2 = k2 ? col[e2] : 0;
        int c3 = k3 ? col[e3] : 0;
        uint4 r0 = *(const uint4*)(g + (((long long)c0) << 6) + (c << 3));
        uint4 r1 = *(const uint4*)(g + (((long long)c1) << 6) + (c << 3));
        uint4 r2 = *(const uint4*)(g + (((long long)c2) << 6) + (c << 3));
        uint4 r3 = *(const uint4*)(g + (((long long)c3) << 6) + (c << 3));
        if (k0) add8(acc, r0);
        if (k1) add8(acc, r1);
        if (k2) add8(acc, r2);
        if (k3) add8(acc, r3);
    }
#pragma unroll
    for (int m = 8; m <= 32; m <<= 1) {
#pragma unroll
        for (int k = 0; k < 8; k++) acc[k] += __shfl_xor(acc[k], m);
    }
    if (lane < 8) {
        float dv = dinv[node];
        float4 ba = *(const float4*)(bias + (lane << 3));
        float4 bb = *(const float4*)(bias + (lane << 3) + 4);
        float v0 = dv * acc[0] + ba.x;
        float v1 = dv * acc[1] + ba.y;
        float v2 = dv * acc[2] + ba.z;
        float v3 = dv * acc[3] + ba.w;
        float v4 = dv * acc[4] + bb.x;
        float v5 = dv * acc[5] + bb.y;
        float v6 = dv * acc[6] + bb.z;
        float v7 = dv * acc[7] + bb.w;
        v0 = v0 > 0.f ? v0 : 0.f;
        v1 = v1 > 0.f ? v1 : 0.f;
        v2 = v2 > 0.f ? v2 : 0.f;
        v3 = v3 > 0.f ? v3 : 0.f;
        v4 = v4 > 0.f ? v4 : 0.f;
        v5 = v5 > 0.f ? v5 : 0.f;
        v6 = v6 > 0.f ? v6 : 0.f;
        v7 = v7 > 0.f ? v7 : 0.f;
        uint4 w;
        w.x = (unsigned)f2bf(v0) | ((unsigned)f2bf(v1) << 16);
        w.y = (unsigned)f2bf(v2) | ((unsigned)f2bf(v3) << 16);
        w.z = (unsigned)f2bf(v4) | ((unsigned)f2bf(v5) << 16);
        w.w = (unsigned)f2bf(v6) | ((unsigned)f2bf(v7) << 16);
        *(uint4*)(h + ((long long)node << 6) + (lane << 3)) = w;
    }
}

// ========== pooling: segmented reduction over sorted batch (sums only) ==========
__global__ void pool_kernel(const unsigned short* __restrict__ h, const int* __restrict__ batch,
                            float* __restrict__ sums, int N) {
    int wave = blockIdx.x * 4 + (threadIdx.x >> 6);
    int lane = threadIdx.x & 63;
    int lo = wave * 16;
    if (lo >= N) return;
    int hi = min(lo + 16, N);
    int curb = batch[lo];
    float sum = 0.f;
    for (int i = lo; i < hi; i++) {
        int b = batch[i];
        if (b != curb) {
            atomicAdd(&sums[curb * HID + lane], sum);
            curb = b; sum = 0.f;
        }
        sum += bf2f(h[(long long)i * HID + lane]);
    }
    atomicAdd(&sums[curb * HID + lane], sum);
}

// ================= final MLP head (cnt via binary search on sorted batch) =========
__global__ void final_kernel(const float* __restrict__ sums, const int* __restrict__ batch,
                             const float* __restrict__ Wf1, const float* __restrict__ bf1,
                             const float* __restrict__ Wf2, const float* __restrict__ bf2,
                             float* __restrict__ out, int N) {
    __shared__ float sW1[HID * 32];
    __shared__ float sW2[32];
    __shared__ int sUB[128];
    int tid = threadIdx.x;
    for (int idx = tid; idx < HID * 32; idx += 128) sW1[idx] = Wf1[idx];
    if (tid < 32) sW2[tid] = Wf2[tid];
    // upper_bound(batch, tid): first index with batch[i] > tid
    {
        int lo = 0, hi = N;
        while (lo < hi) {
            int mid = (lo + hi) >> 1;
            if (batch[mid] <= tid) lo = mid + 1; else hi = mid;
        }
        sUB[tid] = lo;
    }
    __syncthreads();
    int b = tid;
    float c = (float)(sUB[b] - (b ? sUB[b - 1] : 0));
    c = fmaxf(c, 1.0f);
    float pooled[HID];
#pragma unroll
    for (int j = 0; j < HID; j++) pooled[j] = sums[b * HID + j] / c;
    float o = bf2[0];
#pragma unroll 4
    for (int hd = 0; hd < 32; hd++) {
        float z = bf1[hd];
#pragma unroll
        for (int j = 0; j < HID; j++) z += pooled[j] * sW1[j * 32 + hd];
        z = fmaxf(z, 0.f);
        o += z * sW2[hd];
    }
    out[b] = o;
}

extern "C" void kernel_launch(void* const* d_in, const int* in_sizes, int n_in,
                              void* d_out, int out_size, void* d_ws, size_t ws_size,
                              hipStream_t stream) {
    const float* x     = (const float*)d_in[0];
    const int*   ei    = (const int*)d_in[1];
    const int*   batch = (const int*)d_in[3];
    const float* W1  = (const float*)d_in[4];
    const float* b1  = (const float*)d_in[5];
    const float* W2  = (const float*)d_in[6];
    const float* b2  = (const float*)d_in[7];
    const float* W3  = (const float*)d_in[8];
    const float* b3  = (const float*)d_in[9];
    const float* Wf1 = (const float*)d_in[10];
    const float* bf1 = (const float*)d_in[11];
    const float* Wf2 = (const float*)d_in[12];
    const float* bf2 = (const float*)d_in[13];
    float* out = (float*)d_out;

    const int N  = in_sizes[0] / 16;   // 100000
    const int E  = in_sizes[1] / 2;    // 3200000
    const int NB = (N + 63) / 64;      // 1563 buckets

    // workspace layout (~72 MB), fixed-capacity padded ebuf/col segments
    char* ws = (char*)d_ws;
    size_t o = 0;
    float*          dinv    = (float*)(ws + o);          o += ((size_t)N * 4 + 4095) / 4096 * 4096;
    int*            row_ptr = (int*)(ws + o);            o += ((size_t)N * 4 + 4095) / 4096 * 4096;
    int*            rend    = (int*)(ws + o);            o += ((size_t)N * 4 + 4095) / 4096 * 4096;
    int*            gcur    = (int*)(ws + o);            o += ((size_t)NB * 4 + 4095) / 4096 * 4096;
    unsigned*       ebuf    = (unsigned*)(ws + o);       o += (size_t)NB * SEG_CAP * 4;
    int*            col     = (int*)(ws + o);            o += (size_t)NB * SEG_CAP * 4;
    unsigned short* A       = (unsigned short*)(ws + o); o += (size_t)N * HID * 2;
    unsigned short* B       = (unsigned short*)(ws + o); o += (size_t)N * HID * 2;
    unsigned short* XS      = (unsigned short*)(ws + o); o += ((size_t)N * 16 * 2 + 4095) / 4096 * 4096;
    float*          AGG     = (float*)(ws + o);          o += ((size_t)N * 16 * 4 + 4095) / 4096 * 4096;
    float*          sums    = (float*)(ws + o);          o += 128 * HID * 4;
    (void)ws_size;

    const int T = 256;
    const int Cchunk = (((E + NBLK - 1) / NBLK) + 3) & ~3;   // mult of 4 for int4 loads
    const int gGm = (N + 15) / 16;
    const int gGa = (N + 3) / 4;
    const int gPool = ((N + 15) / 16 + 3) / 4;

    // ---- CSR build: single-pass padded radix partition + per-bucket sort ----
    hipMemsetAsync(gcur, 0, (size_t)NB * 4, stream);
    radix_fill2_kernel<<<NBLK, FILL_T, 0, stream>>>(ei, gcur, ebuf, E, NB, Cchunk);
    node_csr_xs_kernel<<<NB, T, 0, stream>>>(gcur, ebuf, x, row_ptr, rend, col, dinv, XS, sums, N, NB);

    // ---- layer 1+2 front: agg in 16-dim input space (L2-resident), then
    //      fused (agg@W1 -> relu -> @W2) producing g2 directly ----
    gather16_kernel<<<gGa, T, 0, stream>>>(row_ptr, rend, col, XS, AGG, N);
    gemm_agg2_kernel<<<gGm, T, 0, stream>>>(AGG, W1, b1, W2, dinv, A, N);

    // ---- layer 2 back: gather g2 -> h2 ----
    gather_kernel<<<gGa, T, 0, stream>>>(row_ptr, rend, col, A, dinv, b2, B, N);

    // ---- layer 3: h2 -> g3 (in-place) -> gather -> h3 ----
    gemm_g_kernel<unsigned short, 64><<<gGm, T, 0, stream>>>(B, W3, dinv, B, N);
    gather_kernel<<<gGa, T, 0, stream>>>(row_ptr, rend, col, B, dinv, b3, A, N);

    // ---- pool + head ----
    pool_kernel<<<gPool, T, 0, stream>>>(A, batch, sums, N);
    final_kernel<<<1, 128, 0, stream>>>(sums, batch, Wf1, bf1, Wf2, bf2, out, N);
}